// Round 6
// baseline (112.652 us; speedup 1.0000x reference)
//
#include <hip/hip_runtime.h>

#define LN_SIZE 512
#define LN_NWAVES 8192                   // total waves = 2048 blocks x 4 waves
#define LN_ROWS (8192 * 32)              // 262144 rows of 512 floats
#define LN_EPS 1e-5f
#define LN_SCALE 22.62741699796952f      // sqrt(512)
#define RPW 32                           // rows per wave (strided by LN_NWAVES)

typedef float f32x4 __attribute__((ext_vector_type(4)));

// ---------------------------------------------------------------------------
// Fully fused, barrier-free kernel.
//   out[row][j] = (x[row]*A_j + B_j) * r(x[row]) + beta_j
//   A = (w - mean(w))*gamma, B = (b - mean(b))*gamma
//   var = c2*x^2 + c1*x + c0 ; r = sqrt(512)*rsqrt(var+eps)
//
// Row->wave mapping is STRIDED: wave g writes rows {g + 8192*i}. At any
// instant the 8192 resident waves collectively write one dense 16 MiB
// linearly-advancing window — the same single-stream DRAM pattern as the
// 6.7 TB/s fillBuffer kernel — instead of 8192 independent 64 KiB streams.
// Store loop remains load-free: lane l preloads x for iteration l, shfl
// broadcasts per iteration. Moment reduction is per-wave (butterfly shfl),
// no LDS, no __syncthreads. Plain cached stores (nt stores were 2.3x slower
// on gfx950 — R4 post-mortem).
// ---------------------------------------------------------------------------
__global__ __launch_bounds__(256) void ln_fused_kernel(
    const float* __restrict__ x, const float* __restrict__ w,
    const float* __restrict__ b, const float* __restrict__ gamma,
    const float* __restrict__ beta, float* __restrict__ out) {
  const int tid  = (int)threadIdx.x;
  const int lane = tid & 63;
  const int g    = (int)((blockIdx.x * blockDim.x + tid) >> 6);  // wave id
  const int j    = lane * 8;

  // ---- preload this wave's 32 x values: lane l <-> row g + 8192*l ----
  const float xv = x[g + LN_NWAVES * (lane & 31)];

  // ---- per-lane column data (8 columns per lane) ----
  const float4 wv0 = *(const float4*)(w + j);
  const float4 wv1 = *(const float4*)(w + j + 4);
  const float4 bv0 = *(const float4*)(b + j);
  const float4 bv1 = *(const float4*)(b + j + 4);
  const float4 gv0 = *(const float4*)(gamma + j);
  const float4 gv1 = *(const float4*)(gamma + j + 4);
  const float4 g0  = *(const float4*)(beta + j);
  const float4 g1  = *(const float4*)(beta + j + 4);

  // ---- per-wave 5-moment butterfly reduction (no LDS, no barrier) ----
  float sw  = wv0.x + wv0.y + wv0.z + wv0.w + wv1.x + wv1.y + wv1.z + wv1.w;
  float sb  = bv0.x + bv0.y + bv0.z + bv0.w + bv1.x + bv1.y + bv1.z + bv1.w;
  float sww = wv0.x*wv0.x + wv0.y*wv0.y + wv0.z*wv0.z + wv0.w*wv0.w
            + wv1.x*wv1.x + wv1.y*wv1.y + wv1.z*wv1.z + wv1.w*wv1.w;
  float swb = wv0.x*bv0.x + wv0.y*bv0.y + wv0.z*bv0.z + wv0.w*bv0.w
            + wv1.x*bv1.x + wv1.y*bv1.y + wv1.z*bv1.z + wv1.w*bv1.w;
  float sbb = bv0.x*bv0.x + bv0.y*bv0.y + bv0.z*bv0.z + bv0.w*bv0.w
            + bv1.x*bv1.x + bv1.y*bv1.y + bv1.z*bv1.z + bv1.w*bv1.w;
#pragma unroll
  for (int off = 32; off > 0; off >>= 1) {
    sw  += __shfl_xor(sw, off);
    sb  += __shfl_xor(sb, off);
    sww += __shfl_xor(sww, off);
    swb += __shfl_xor(swb, off);
    sbb += __shfl_xor(sbb, off);
  }

  const float inv_n = 1.0f / (float)LN_SIZE;
  const float mw  = sw * inv_n;
  const float mb  = sb * inv_n;
  const float Sww = sww * inv_n - mw * mw;
  const float Swb = swb * inv_n - mw * mb;
  const float Sbb = sbb * inv_n - mb * mb;
  const float c2 = (float)LN_SIZE * Sww;
  const float c1 = 2.0f * (float)LN_SIZE * Swb;
  const float c0 = (float)LN_SIZE * Sbb;

  float4 a0, a1, B0, B1;
  a0.x = (wv0.x - mw) * gv0.x;  a0.y = (wv0.y - mw) * gv0.y;
  a0.z = (wv0.z - mw) * gv0.z;  a0.w = (wv0.w - mw) * gv0.w;
  a1.x = (wv1.x - mw) * gv1.x;  a1.y = (wv1.y - mw) * gv1.y;
  a1.z = (wv1.z - mw) * gv1.z;  a1.w = (wv1.w - mw) * gv1.w;
  B0.x = (bv0.x - mb) * gv0.x;  B0.y = (bv0.y - mb) * gv0.y;
  B0.z = (bv0.z - mb) * gv0.z;  B0.w = (bv0.w - mb) * gv0.w;
  B1.x = (bv1.x - mb) * gv1.x;  B1.y = (bv1.y - mb) * gv1.y;
  B1.z = (bv1.z - mb) * gv1.z;  B1.w = (bv1.w - mb) * gv1.w;

  // ---- per-row scale factors for this wave's 32 rows ----
  const float var = fmaf(fmaf(c2, xv, c1), xv, c0);
  const float rv  = LN_SCALE * rsqrtf(var + LN_EPS);

  float* dst = out + (size_t)g * LN_SIZE + j;
#pragma unroll
  for (int i = 0; i < RPW; ++i) {
    const float xi = __shfl(xv, i);
    const float ri = __shfl(rv, i);

    f32x4 o0, o1;
    o0.x = fmaf(fmaf(xi, a0.x, B0.x), ri, g0.x);
    o0.y = fmaf(fmaf(xi, a0.y, B0.y), ri, g0.y);
    o0.z = fmaf(fmaf(xi, a0.z, B0.z), ri, g0.z);
    o0.w = fmaf(fmaf(xi, a0.w, B0.w), ri, g0.w);
    o1.x = fmaf(fmaf(xi, a1.x, B1.x), ri, g1.x);
    o1.y = fmaf(fmaf(xi, a1.y, B1.y), ri, g1.y);
    o1.z = fmaf(fmaf(xi, a1.z, B1.z), ri, g1.z);
    o1.w = fmaf(fmaf(xi, a1.w, B1.w), ri, g1.w);

    *(f32x4*)(dst)     = o0;
    *(f32x4*)(dst + 4) = o1;
    dst += (size_t)LN_NWAVES * LN_SIZE;   // advance 16 MiB: global linear sweep
  }
}

extern "C" void kernel_launch(void* const* d_in, const int* in_sizes, int n_in,
                              void* d_out, int out_size, void* d_ws, size_t ws_size,
                              hipStream_t stream) {
  const float* x     = (const float*)d_in[0];
  const float* w     = (const float*)d_in[1];
  const float* b     = (const float*)d_in[2];
  const float* gamma = (const float*)d_in[3];
  const float* beta  = (const float*)d_in[4];
  float* out = (float*)d_out;
  (void)d_ws; (void)ws_size;

  // 2048 blocks x 256 threads = 8192 waves (256 CU x 32 waves);
  // wave g writes rows {g + 8192*i : i<32}.
  ln_fused_kernel<<<2048, 256, 0, stream>>>(x, w, b, gamma, beta, out);
}

// Round 7
// 103.711 us; speedup vs baseline: 1.0862x; 1.0862x over previous
//
#include <hip/hip_runtime.h>

#define LN_SIZE 512
#define LN_ROWS (8192 * 32)              // 262144 rows of 512 floats
#define LN_EPS 1e-5f
#define LN_SCALE 22.62741699796952f      // sqrt(512)
#define RPW 64                           // rows per wave (contiguous 128 KiB)
#define LN_NWAVES (LN_ROWS / RPW)        // 4096 waves = 1024 blocks x 4

typedef float f32x4 __attribute__((ext_vector_type(4)));

// ---------------------------------------------------------------------------
// Fully fused, barrier-free kernel.
//   out[row][j] = (x[row]*A_j + B_j) * r(x[row]) + beta_j
//   A = (w - mean(w))*gamma, B = (b - mean(b))*gamma
//   var = c2*x^2 + c1*x + c0 ; r = sqrt(512)*rsqrt(var+eps)
//
// Mapping: wave g owns 64 CONTIGUOUS rows (128 KiB). Per-wave contiguity is
// what DRAM likes (R6 falsified the global-interleave theory: strided rows
// cost +12%). Store loop is load-free: lane l preloads x[row0+l]; shfl
// broadcasts (xi, ri) per row. Moment reduction is per-wave butterfly —
// no LDS, no __syncthreads. Plain cached stores (nt = 2.3x slower, R4).
// ---------------------------------------------------------------------------
__global__ __launch_bounds__(256) void ln_fused_kernel(
    const float* __restrict__ x, const float* __restrict__ w,
    const float* __restrict__ b, const float* __restrict__ gamma,
    const float* __restrict__ beta, float* __restrict__ out) {
  const int tid  = (int)threadIdx.x;
  const int lane = tid & 63;
  const int g    = (int)((blockIdx.x * blockDim.x + tid) >> 6);  // wave id
  const int j    = lane * 8;
  const int row0 = g * RPW;

  // ---- preload this wave's 64 x values: lane l <-> row row0 + l ----
  const float xv = x[row0 + lane];

  // ---- per-lane column data (8 columns per lane) ----
  const float4 wv0 = *(const float4*)(w + j);
  const float4 wv1 = *(const float4*)(w + j + 4);
  const float4 bv0 = *(const float4*)(b + j);
  const float4 bv1 = *(const float4*)(b + j + 4);
  const float4 gv0 = *(const float4*)(gamma + j);
  const float4 gv1 = *(const float4*)(gamma + j + 4);
  const float4 g0  = *(const float4*)(beta + j);
  const float4 g1  = *(const float4*)(beta + j + 4);

  // ---- per-wave 5-moment butterfly reduction (no LDS, no barrier) ----
  float sw  = wv0.x + wv0.y + wv0.z + wv0.w + wv1.x + wv1.y + wv1.z + wv1.w;
  float sb  = bv0.x + bv0.y + bv0.z + bv0.w + bv1.x + bv1.y + bv1.z + bv1.w;
  float sww = wv0.x*wv0.x + wv0.y*wv0.y + wv0.z*wv0.z + wv0.w*wv0.w
            + wv1.x*wv1.x + wv1.y*wv1.y + wv1.z*wv1.z + wv1.w*wv1.w;
  float swb = wv0.x*bv0.x + wv0.y*bv0.y + wv0.z*bv0.z + wv0.w*bv0.w
            + wv1.x*bv1.x + wv1.y*bv1.y + wv1.z*bv1.z + wv1.w*bv1.w;
  float sbb = bv0.x*bv0.x + bv0.y*bv0.y + bv0.z*bv0.z + bv0.w*bv0.w
            + bv1.x*bv1.x + bv1.y*bv1.y + bv1.z*bv1.z + bv1.w*bv1.w;
#pragma unroll
  for (int off = 32; off > 0; off >>= 1) {
    sw  += __shfl_xor(sw, off);
    sb  += __shfl_xor(sb, off);
    sww += __shfl_xor(sww, off);
    swb += __shfl_xor(swb, off);
    sbb += __shfl_xor(sbb, off);
  }

  const float inv_n = 1.0f / (float)LN_SIZE;
  const float mw  = sw * inv_n;
  const float mb  = sb * inv_n;
  const float Sww = sww * inv_n - mw * mw;
  const float Swb = swb * inv_n - mw * mb;
  const float Sbb = sbb * inv_n - mb * mb;
  const float c2 = (float)LN_SIZE * Sww;
  const float c1 = 2.0f * (float)LN_SIZE * Swb;
  const float c0 = (float)LN_SIZE * Sbb;

  float4 a0, a1, B0, B1;
  a0.x = (wv0.x - mw) * gv0.x;  a0.y = (wv0.y - mw) * gv0.y;
  a0.z = (wv0.z - mw) * gv0.z;  a0.w = (wv0.w - mw) * gv0.w;
  a1.x = (wv1.x - mw) * gv1.x;  a1.y = (wv1.y - mw) * gv1.y;
  a1.z = (wv1.z - mw) * gv1.z;  a1.w = (wv1.w - mw) * gv1.w;
  B0.x = (bv0.x - mb) * gv0.x;  B0.y = (bv0.y - mb) * gv0.y;
  B0.z = (bv0.z - mb) * gv0.z;  B0.w = (bv0.w - mb) * gv0.w;
  B1.x = (bv1.x - mb) * gv1.x;  B1.y = (bv1.y - mb) * gv1.y;
  B1.z = (bv1.z - mb) * gv1.z;  B1.w = (bv1.w - mb) * gv1.w;

  // ---- per-row scale factor (lane l computes row row0+l's) ----
  const float var = fmaf(fmaf(c2, xv, c1), xv, c0);
  const float rv  = LN_SCALE * rsqrtf(var + LN_EPS);

  float* dst = out + (size_t)row0 * LN_SIZE + j;
#pragma unroll
  for (int i = 0; i < RPW; ++i) {
    const float xi = __shfl(xv, i);
    const float ri = __shfl(rv, i);

    f32x4 o0, o1;
    o0.x = fmaf(fmaf(xi, a0.x, B0.x), ri, g0.x);
    o0.y = fmaf(fmaf(xi, a0.y, B0.y), ri, g0.y);
    o0.z = fmaf(fmaf(xi, a0.z, B0.z), ri, g0.z);
    o0.w = fmaf(fmaf(xi, a0.w, B0.w), ri, g0.w);
    o1.x = fmaf(fmaf(xi, a1.x, B1.x), ri, g1.x);
    o1.y = fmaf(fmaf(xi, a1.y, B1.y), ri, g1.y);
    o1.z = fmaf(fmaf(xi, a1.z, B1.z), ri, g1.z);
    o1.w = fmaf(fmaf(xi, a1.w, B1.w), ri, g1.w);

    *(f32x4*)(dst)     = o0;
    *(f32x4*)(dst + 4) = o1;
    dst += LN_SIZE;
  }
}

extern "C" void kernel_launch(void* const* d_in, const int* in_sizes, int n_in,
                              void* d_out, int out_size, void* d_ws, size_t ws_size,
                              hipStream_t stream) {
  const float* x     = (const float*)d_in[0];
  const float* w     = (const float*)d_in[1];
  const float* b     = (const float*)d_in[2];
  const float* gamma = (const float*)d_in[3];
  const float* beta  = (const float*)d_in[4];
  float* out = (float*)d_out;
  (void)d_ws; (void)ws_size;

  // 1024 blocks x 256 threads = 4096 waves (16 waves/CU);
  // wave g writes rows [64g, 64g+64) — 128 KiB contiguous each.
  ln_fused_kernel<<<1024, 256, 0, stream>>>(x, w, b, gamma, beta, out);
}

// Round 8
// 99.874 us; speedup vs baseline: 1.1279x; 1.0384x over previous
//
#include <hip/hip_runtime.h>

#define LN_SIZE 512
#define LN_ROWS (8192 * 32)              // 262144 rows of 512 floats
#define LN_EPS 1e-5f
#define LN_SCALE 22.62741699796952f      // sqrt(512)
#define RPW 32                           // rows per wave (contiguous 64 KiB)

typedef float f32x4 __attribute__((ext_vector_type(4)));

// ---------------------------------------------------------------------------
// Fully fused, barrier-free kernel.
//   out[row][j] = (x[row]*A_j + B_j) * r(x[row]) + beta_j
//   A = (w - mean(w))*gamma, B = (b - mean(b))*gamma
//   var = c2*x^2 + c1*x + c0 ; r = sqrt(512)*rsqrt(var+eps)
//
// Column partitioning is chosen so each wave-wide store is a FULLY
// CONTIGUOUS 1 KiB span (lane l owns cols [4l,4l+4) and [256+4l,256+4l+4)):
// store0 covers row bytes [0,1024), store1 covers [1024,2048) — identical
// instruction-level pattern to the 6.7 TB/s fillBuffer kernel. (The previous
// lane*8 layout made each store a stride-32B half-sector pattern.)
// Mapping: wave g owns 32 contiguous rows (64 KiB) — R6 falsified global
// interleave; R7 falsified bigger regions. Store loop is load-free (x via
// shfl). Per-wave butterfly moment reduction — no LDS, no barriers. Plain
// cached stores (nt = 2.3x slower on gfx950, R4).
// ---------------------------------------------------------------------------
__global__ __launch_bounds__(256) void ln_fused_kernel(
    const float* __restrict__ x, const float* __restrict__ w,
    const float* __restrict__ b, const float* __restrict__ gamma,
    const float* __restrict__ beta, float* __restrict__ out) {
  const int tid  = (int)threadIdx.x;
  const int lane = tid & 63;
  const int g    = (int)((blockIdx.x * blockDim.x + tid) >> 6);  // wave id
  const int l4   = lane * 4;
  const int row0 = g * RPW;

  // ---- preload this wave's 32 x values: lane l <-> row row0 + (l&31) ----
  const float xv = x[row0 + (lane & 31)];

  // ---- per-lane column data: cols [l4,l4+4) and [256+l4,256+l4+4) ----
  const float4 wv0 = *(const float4*)(w + l4);
  const float4 wv1 = *(const float4*)(w + 256 + l4);
  const float4 bv0 = *(const float4*)(b + l4);
  const float4 bv1 = *(const float4*)(b + 256 + l4);
  const float4 gv0 = *(const float4*)(gamma + l4);
  const float4 gv1 = *(const float4*)(gamma + 256 + l4);
  const float4 g0  = *(const float4*)(beta + l4);
  const float4 g1  = *(const float4*)(beta + 256 + l4);

  // ---- per-wave 5-moment butterfly reduction (no LDS, no barrier) ----
  float sw  = wv0.x + wv0.y + wv0.z + wv0.w + wv1.x + wv1.y + wv1.z + wv1.w;
  float sb  = bv0.x + bv0.y + bv0.z + bv0.w + bv1.x + bv1.y + bv1.z + bv1.w;
  float sww = wv0.x*wv0.x + wv0.y*wv0.y + wv0.z*wv0.z + wv0.w*wv0.w
            + wv1.x*wv1.x + wv1.y*wv1.y + wv1.z*wv1.z + wv1.w*wv1.w;
  float swb = wv0.x*bv0.x + wv0.y*bv0.y + wv0.z*bv0.z + wv0.w*bv0.w
            + wv1.x*bv1.x + wv1.y*bv1.y + wv1.z*bv1.z + wv1.w*bv1.w;
  float sbb = bv0.x*bv0.x + bv0.y*bv0.y + bv0.z*bv0.z + bv0.w*bv0.w
            + bv1.x*bv1.x + bv1.y*bv1.y + bv1.z*bv1.z + bv1.w*bv1.w;
#pragma unroll
  for (int off = 32; off > 0; off >>= 1) {
    sw  += __shfl_xor(sw, off);
    sb  += __shfl_xor(sb, off);
    sww += __shfl_xor(sww, off);
    swb += __shfl_xor(swb, off);
    sbb += __shfl_xor(sbb, off);
  }

  const float inv_n = 1.0f / (float)LN_SIZE;
  const float mw  = sw * inv_n;
  const float mb  = sb * inv_n;
  const float Sww = sww * inv_n - mw * mw;
  const float Swb = swb * inv_n - mw * mb;
  const float Sbb = sbb * inv_n - mb * mb;
  const float c2 = (float)LN_SIZE * Sww;
  const float c1 = 2.0f * (float)LN_SIZE * Swb;
  const float c0 = (float)LN_SIZE * Sbb;

  float4 a0, a1, B0, B1;
  a0.x = (wv0.x - mw) * gv0.x;  a0.y = (wv0.y - mw) * gv0.y;
  a0.z = (wv0.z - mw) * gv0.z;  a0.w = (wv0.w - mw) * gv0.w;
  a1.x = (wv1.x - mw) * gv1.x;  a1.y = (wv1.y - mw) * gv1.y;
  a1.z = (wv1.z - mw) * gv1.z;  a1.w = (wv1.w - mw) * gv1.w;
  B0.x = (bv0.x - mb) * gv0.x;  B0.y = (bv0.y - mb) * gv0.y;
  B0.z = (bv0.z - mb) * gv0.z;  B0.w = (bv0.w - mb) * gv0.w;
  B1.x = (bv1.x - mb) * gv1.x;  B1.y = (bv1.y - mb) * gv1.y;
  B1.z = (bv1.z - mb) * gv1.z;  B1.w = (bv1.w - mb) * gv1.w;

  // ---- per-row scale factor ----
  const float var = fmaf(fmaf(c2, xv, c1), xv, c0);
  const float rv  = LN_SCALE * rsqrtf(var + LN_EPS);

  float* rowp = out + (size_t)row0 * LN_SIZE + l4;
#pragma unroll
  for (int i = 0; i < RPW; ++i) {
    const float xi = __shfl(xv, i);
    const float ri = __shfl(rv, i);

    f32x4 o0, o1;
    o0.x = fmaf(fmaf(xi, a0.x, B0.x), ri, g0.x);
    o0.y = fmaf(fmaf(xi, a0.y, B0.y), ri, g0.y);
    o0.z = fmaf(fmaf(xi, a0.z, B0.z), ri, g0.z);
    o0.w = fmaf(fmaf(xi, a0.w, B0.w), ri, g0.w);
    o1.x = fmaf(fmaf(xi, a1.x, B1.x), ri, g1.x);
    o1.y = fmaf(fmaf(xi, a1.y, B1.y), ri, g1.y);
    o1.z = fmaf(fmaf(xi, a1.z, B1.z), ri, g1.z);
    o1.w = fmaf(fmaf(xi, a1.w, B1.w), ri, g1.w);

    *(f32x4*)(rowp)       = o0;   // bytes [0,1024) of row — contiguous
    *(f32x4*)(rowp + 256) = o1;   // bytes [1024,2048)    — contiguous
    rowp += LN_SIZE;
  }
}

extern "C" void kernel_launch(void* const* d_in, const int* in_sizes, int n_in,
                              void* d_out, int out_size, void* d_ws, size_t ws_size,
                              hipStream_t stream) {
  const float* x     = (const float*)d_in[0];
  const float* w     = (const float*)d_in[1];
  const float* b     = (const float*)d_in[2];
  const float* gamma = (const float*)d_in[3];
  const float* beta  = (const float*)d_in[4];
  float* out = (float*)d_out;
  (void)d_ws; (void)ws_size;

  // 2048 blocks x 256 threads = 8192 waves (256 CU x 32 waves);
  // wave g writes rows [32g, 32g+32) — 64 KiB contiguous each.
  ln_fused_kernel<<<2048, 256, 0, stream>>>(x, w, b, gamma, beta, out);
}

// Round 9
// 99.150 us; speedup vs baseline: 1.1362x; 1.0073x over previous
//
#include <hip/hip_runtime.h>

#define LN_SIZE 512
#define LN_ROWS (8192 * 32)              // 262144 rows of 512 floats
#define LN_EPS 1e-5f
#define LN_SCALE 22.62741699796952f      // sqrt(512)
#define RPW 32                           // rows per wave (contiguous 64 KiB)
#define CHUNK 8                          // rows per hoisted burst

typedef float f32x4 __attribute__((ext_vector_type(4)));

// ---------------------------------------------------------------------------
// Fully fused, barrier-free kernel.
//   out[row][j] = (x[row]*A_j + B_j) * r(x[row]) + beta_j
//   A = (w - mean(w))*gamma, B = (b - mean(b))*gamma
//   var = c2*x^2 + c1*x + c0 ; r = sqrt(512)*rsqrt(var+eps)
//
// R9 change: the store loop is restructured into 4 chunks of 8 rows. Each
// chunk first hoists the 8 (xi, ri) wave-uniform pairs via shfl into
// registers (compile-time indices -> no scratch), then issues 16
// dependency-free wave-wide stores back-to-back (32 KiB burst). Previously
// every 2 stores were separated by 2 dependent ds_bpermute + FMA chain,
// arriving at L2 as latency-gapped puffs. Mapping unchanged (wave g owns 32
// contiguous rows; R6 falsified global interleave, R7 falsified bigger
// regions). Full-span 1 KiB stores per instruction (R8). Plain cached
// stores (nt = 2.3x slower, R4). No LDS, no barriers.
// ---------------------------------------------------------------------------
__global__ __launch_bounds__(256) void ln_fused_kernel(
    const float* __restrict__ x, const float* __restrict__ w,
    const float* __restrict__ b, const float* __restrict__ gamma,
    const float* __restrict__ beta, float* __restrict__ out) {
  const int tid  = (int)threadIdx.x;
  const int lane = tid & 63;
  const int g    = (int)((blockIdx.x * blockDim.x + tid) >> 6);  // wave id
  const int l4   = lane * 4;
  const int row0 = g * RPW;

  // ---- preload this wave's 32 x values: lane l <-> row row0 + (l&31) ----
  const float xv = x[row0 + (lane & 31)];

  // ---- per-lane column data: cols [l4,l4+4) and [256+l4,256+l4+4) ----
  const float4 wv0 = *(const float4*)(w + l4);
  const float4 wv1 = *(const float4*)(w + 256 + l4);
  const float4 bv0 = *(const float4*)(b + l4);
  const float4 bv1 = *(const float4*)(b + 256 + l4);
  const float4 gv0 = *(const float4*)(gamma + l4);
  const float4 gv1 = *(const float4*)(gamma + 256 + l4);
  const float4 g0  = *(const float4*)(beta + l4);
  const float4 g1  = *(const float4*)(beta + 256 + l4);

  // ---- per-wave 5-moment butterfly reduction (no LDS, no barrier) ----
  float sw  = wv0.x + wv0.y + wv0.z + wv0.w + wv1.x + wv1.y + wv1.z + wv1.w;
  float sb  = bv0.x + bv0.y + bv0.z + bv0.w + bv1.x + bv1.y + bv1.z + bv1.w;
  float sww = wv0.x*wv0.x + wv0.y*wv0.y + wv0.z*wv0.z + wv0.w*wv0.w
            + wv1.x*wv1.x + wv1.y*wv1.y + wv1.z*wv1.z + wv1.w*wv1.w;
  float swb = wv0.x*bv0.x + wv0.y*bv0.y + wv0.z*bv0.z + wv0.w*bv0.w
            + wv1.x*bv1.x + wv1.y*bv1.y + wv1.z*bv1.z + wv1.w*bv1.w;
  float sbb = bv0.x*bv0.x + bv0.y*bv0.y + bv0.z*bv0.z + bv0.w*bv0.w
            + bv1.x*bv1.x + bv1.y*bv1.y + bv1.z*bv1.z + bv1.w*bv1.w;
#pragma unroll
  for (int off = 32; off > 0; off >>= 1) {
    sw  += __shfl_xor(sw, off);
    sb  += __shfl_xor(sb, off);
    sww += __shfl_xor(sww, off);
    swb += __shfl_xor(swb, off);
    sbb += __shfl_xor(sbb, off);
  }

  const float inv_n = 1.0f / (float)LN_SIZE;
  const float mw  = sw * inv_n;
  const float mb  = sb * inv_n;
  const float Sww = sww * inv_n - mw * mw;
  const float Swb = swb * inv_n - mw * mb;
  const float Sbb = sbb * inv_n - mb * mb;
  const float c2 = (float)LN_SIZE * Sww;
  const float c1 = 2.0f * (float)LN_SIZE * Swb;
  const float c0 = (float)LN_SIZE * Sbb;

  float4 a0, a1, B0, B1;
  a0.x = (wv0.x - mw) * gv0.x;  a0.y = (wv0.y - mw) * gv0.y;
  a0.z = (wv0.z - mw) * gv0.z;  a0.w = (wv0.w - mw) * gv0.w;
  a1.x = (wv1.x - mw) * gv1.x;  a1.y = (wv1.y - mw) * gv1.y;
  a1.z = (wv1.z - mw) * gv1.z;  a1.w = (wv1.w - mw) * gv1.w;
  B0.x = (bv0.x - mb) * gv0.x;  B0.y = (bv0.y - mb) * gv0.y;
  B0.z = (bv0.z - mb) * gv0.z;  B0.w = (bv0.w - mb) * gv0.w;
  B1.x = (bv1.x - mb) * gv1.x;  B1.y = (bv1.y - mb) * gv1.y;
  B1.z = (bv1.z - mb) * gv1.z;  B1.w = (bv1.w - mb) * gv1.w;

  // ---- per-row scale factor ----
  const float var = fmaf(fmaf(c2, xv, c1), xv, c0);
  const float rv  = LN_SCALE * rsqrtf(var + LN_EPS);

  float* rowp = out + (size_t)row0 * LN_SIZE + l4;
#pragma unroll
  for (int c = 0; c < RPW / CHUNK; ++c) {
    // Hoist 8 rows' wave-uniform scalars (compile-time lane indices).
    float xs[CHUNK], rs[CHUNK];
#pragma unroll
    for (int k = 0; k < CHUNK; ++k) {
      xs[k] = __shfl(xv, c * CHUNK + k);
      rs[k] = __shfl(rv, c * CHUNK + k);
    }
    // Dependency-free burst: 16 wave-wide stores (32 KiB).
#pragma unroll
    for (int k = 0; k < CHUNK; ++k) {
      const float xi = xs[k];
      const float ri = rs[k];
      f32x4 o0, o1;
      o0.x = fmaf(fmaf(xi, a0.x, B0.x), ri, g0.x);
      o0.y = fmaf(fmaf(xi, a0.y, B0.y), ri, g0.y);
      o0.z = fmaf(fmaf(xi, a0.z, B0.z), ri, g0.z);
      o0.w = fmaf(fmaf(xi, a0.w, B0.w), ri, g0.w);
      o1.x = fmaf(fmaf(xi, a1.x, B1.x), ri, g1.x);
      o1.y = fmaf(fmaf(xi, a1.y, B1.y), ri, g1.y);
      o1.z = fmaf(fmaf(xi, a1.z, B1.z), ri, g1.z);
      o1.w = fmaf(fmaf(xi, a1.w, B1.w), ri, g1.w);

      *(f32x4*)(rowp)       = o0;   // row bytes [0,1024)
      *(f32x4*)(rowp + 256) = o1;   // row bytes [1024,2048)
      rowp += LN_SIZE;
    }
  }
}

extern "C" void kernel_launch(void* const* d_in, const int* in_sizes, int n_in,
                              void* d_out, int out_size, void* d_ws, size_t ws_size,
                              hipStream_t stream) {
  const float* x     = (const float*)d_in[0];
  const float* w     = (const float*)d_in[1];
  const float* b     = (const float*)d_in[2];
  const float* gamma = (const float*)d_in[3];
  const float* beta  = (const float*)d_in[4];
  float* out = (float*)d_out;
  (void)d_ws; (void)ws_size;

  // 2048 blocks x 256 threads = 8192 waves (256 CU x 32 waves);
  // wave g writes rows [32g, 32g+32) — 64 KiB contiguous each.
  ln_fused_kernel<<<2048, 256, 0, stream>>>(x, w, b, gamma, beta, out);
}